// Round 12
// baseline (315.931 us; speedup 1.0000x reference)
//
#include <hip/hip_runtime.h>

typedef unsigned short u16;
typedef unsigned int u32;
typedef __bf16 bf16x8 __attribute__((ext_vector_type(8)));
typedef float f32x4 __attribute__((ext_vector_type(4)));

#define MFMA16 __builtin_amdgcn_mfma_f32_16x16x32_bf16
#define NBLK 256
#define WST 168
#define WBST 136
#define BST 114
#define WCHUNK (16 * (WST + WBST + BST))   // 6688 u16 per wave's LDS chunk

__device__ __forceinline__ u16 f2bf(float f) {
    u32 u = __float_as_uint(f);
    u32 r = (u + 0x7fffu + ((u >> 16) & 1u)) >> 16;
    return (u16)r;
}
__device__ __forceinline__ float bf2f(u16 h) {
    return __uint_as_float(((u32)h) << 16);
}
__device__ __forceinline__ bf16x8 ld8(const u16* p) {
    return *reinterpret_cast<const bf16x8*>(p);
}

// Grid barrier, poison-proof: 0xAAAAAAAA (re-poisoned ws) is negative as int,
// fresh-zero pages are 0 -> both spin until this launch's phase value lands.
// Phases only increase within a launch, so early blocks can't deadlock late ones.
__device__ __forceinline__ void gsync(u32* flags, int p) {
    __syncthreads();
    if (threadIdx.x == 0) {
        __threadfence();
        __hip_atomic_store(&flags[blockIdx.x], (u32)p, __ATOMIC_RELEASE,
                           __HIP_MEMORY_SCOPE_AGENT);
    }
    while ((int)__hip_atomic_load(&flags[threadIdx.x], __ATOMIC_ACQUIRE,
                                  __HIP_MEMORY_SCOPE_AGENT) < p) {
        __builtin_amdgcn_s_sleep(2);
    }
    __threadfence();
    __syncthreads();
}

__global__ __launch_bounds__(256, 1) void fused_all(
    const float* __restrict__ x,
    const float* __restrict__ Wc, const float* __restrict__ bc,
    const float* __restrict__ Wq, const float* __restrict__ bq,
    const float* __restrict__ Wk, const float* __restrict__ bk,
    const float* __restrict__ emb,
    const float* __restrict__ Wf, const float* __restrict__ bf,
    const float* __restrict__ gamma, const float* __restrict__ beta,
    const float* __restrict__ scale,
    u16* __restrict__ xT,
    u16* __restrict__ wcb, u16* __restrict__ wqb, u16* __restrict__ wkb,
    u16* __restrict__ wfb, u16* __restrict__ embR, u16* __restrict__ embT,
    u16* __restrict__ qb, u16* __restrict__ kb, u16* __restrict__ cbuf,
    u16* __restrict__ abuf, u16* __restrict__ pbuf,
    u32* __restrict__ flags,
    float* __restrict__ out)
{
    __shared__ u32 smem32[13376];   // 53504 B, aliased per phase
    u16* smem = (u16*)smem32;
    const int tid = threadIdx.x;
    const int blk = blockIdx.x;
    const int wv = tid >> 6, lane = tid & 63;
    const int l15 = lane & 15, kg8 = (lane >> 4) * 8;
    const f32x4 zf = {0.f, 0.f, 0.f, 0.f};

    // ================= P0: prep (x transpose + W/emb convert) =================
    if (blk < 192) {
        const int b = blk / 96, c0 = ((blk / 24) & 3) * 64, l0 = (blk % 24) * 64;
        u16* tile = smem;   // [64][65]
        const int cc = tid >> 2, lq = (tid & 3) * 16;
        const float* xp = x + (size_t)((b * 256 + c0 + cc) * 1536 + l0 + lq);
        #pragma unroll
        for (int i = 0; i < 4; ++i) {
            float4 v = *reinterpret_cast<const float4*>(xp + i * 4);
            tile[cc * 65 + lq + i * 4 + 0] = f2bf(v.x);
            tile[cc * 65 + lq + i * 4 + 1] = f2bf(v.y);
            tile[cc * 65 + lq + i * 4 + 2] = f2bf(v.z);
            tile[cc * 65 + lq + i * 4 + 3] = f2bf(v.w);
        }
        __syncthreads();
        const int ll = tid >> 2, cq = (tid & 3) * 16;
        u16* op = xT + (size_t)((b * 1536 + l0 + ll) * 256 + c0 + cq);
        #pragma unroll
        for (int i = 0; i < 16; ++i) op[i] = tile[(cq + i) * 65 + ll];
    } else {
        const int g = (blk - 192) * 256 + tid;   // [0, 16384)
        #pragma unroll
        for (int rep = 0; rep < 4; ++rep) {
            const int i = g + rep * 16384;
            wcb[i] = f2bf(Wc[i]); wqb[i] = f2bf(Wq[i]);
            wkb[i] = f2bf(Wk[i]); wfb[i] = f2bf(Wf[i]);
        }
        if (g < 112 * 64) {
            const int j = g >> 6, d = g & 63;
            embR[g] = (j < 101) ? f2bf(0.3f * emb[(100 - j) * 64 + d]) : (u16)0;
        }
        if (g < 64 * 128) {
            const int d = g >> 7, j = g & 127;
            embT[g] = (j < 101) ? f2bf(0.3f * emb[(100 - j) * 64 + d]) : (u16)0;
        }
    }
    gsync(flags, 1);

    // ================= P1: q/k/content GEMMs (2304 wave tiles) =================
    for (int u = blk * 4 + wv; u < 2304; u += 1024) {
        const int z = u / 384;
        const int r = u - z * 384;
        const int l0 = (r >> 3) * 32;
        const int ch0 = (r & 7) * 32;
        const int b = z & 1, which = z >> 1;
        const u16* W = (which == 0) ? wqb : (which == 1) ? wkb : wcb;
        const float* bias = (which == 0) ? bq : (which == 1) ? bk : bc;
        const u16* xp = xT + (size_t)(b * 1536 + l0 + l15) * 256 + kg8;
        const u16* wp = W + (size_t)(ch0 + l15) * 256 + kg8;
        const u16* ap = (which == 2) ? wp : xp;
        const u16* bp = (which == 2) ? xp : wp;
        bf16x8 a0r[8], a1r[8], b0r[8], b1r[8];
        #pragma unroll
        for (int kd = 0; kd < 8; ++kd) {
            a0r[kd] = ld8(ap + kd * 32);
            a1r[kd] = ld8(ap + 4096 + kd * 32);
            b0r[kd] = ld8(bp + kd * 32);
            b1r[kd] = ld8(bp + 4096 + kd * 32);
        }
        f32x4 acc[2][2] = {{zf, zf}, {zf, zf}};
        #pragma unroll
        for (int kd = 0; kd < 8; ++kd) {
            acc[0][0] = MFMA16(a0r[kd], b0r[kd], acc[0][0], 0, 0, 0);
            acc[0][1] = MFMA16(a0r[kd], b1r[kd], acc[0][1], 0, 0, 0);
            acc[1][0] = MFMA16(a1r[kd], b0r[kd], acc[1][0], 0, 0, 0);
            acc[1][1] = MFMA16(a1r[kd], b1r[kd], acc[1][1], 0, 0, 0);
        }
        if (which < 2) {
            u16* outp = which ? kb : qb;
            float bv[2];
            bv[0] = bias[ch0 + l15];
            bv[1] = bias[ch0 + 16 + l15];
            #pragma unroll
            for (int mf = 0; mf < 2; ++mf)
                #pragma unroll
                for (int nf = 0; nf < 2; ++nf)
                    #pragma unroll
                    for (int r2 = 0; r2 < 4; ++r2) {
                        const int row = l0 + mf * 16 + (lane >> 4) * 4 + r2;
                        outp[(size_t)(b * 1536 + row) * 256 + ch0 + nf * 16 + l15] =
                            f2bf(acc[mf][nf][r2] + bv[nf]);
                    }
        } else {
            #pragma unroll
            for (int mf = 0; mf < 2; ++mf)
                #pragma unroll
                for (int r2 = 0; r2 < 4; ++r2) {
                    const int ch = ch0 + mf * 16 + (lane >> 4) * 4 + r2;
                    const float bv = bias[ch];
                    #pragma unroll
                    for (int nf = 0; nf < 2; ++nf)
                        cbuf[(size_t)(b * 256 + ch) * 1536 + l0 + nf * 16 + l15] =
                            f2bf(acc[mf][nf][r2] + bv);
                }
        }
    }
    gsync(flags, 2);

    // ================= P2: banded attention (768 wave tiles) =================
    {
        const int u = blk * 4 + wv;
        if (u < 768) {
            const int bh = u / 96;
            const int tt0 = (u - bh * 96) * 16;
            const int b = bh >> 2, h = bh & 3;
            u16* wl = smem + wv * WCHUNK;
            u16* wb = wl + 16 * WST;
            u16* bs = wb + 16 * WBST;

            const u16* qp = qb + (size_t)(b * 1536 + tt0 + l15) * 256 + h * 64 + kg8;
            const bf16x8 a0 = ld8(qp);
            const bf16x8 a1 = ld8(qp + 32);
            bf16x8 k0r[9], k1r[9];
            #pragma unroll
            for (int nf = 0; nf < 9; ++nf) {
                int s = tt0 - 64 + nf * 16 + l15;
                int sc = s < 0 ? 0 : (s > 1535 ? 1535 : s);
                const u16* kp = kb + (size_t)(b * 1536 + sc) * 256 + h * 64 + kg8;
                k0r[nf] = ld8(kp);
                k1r[nf] = ld8(kp + 32);
            }
            for (int i = lane; i < 16 * 8; i += 64) {
                const int t = i >> 3, c = 144 + ((i & 7) << 1);
                *reinterpret_cast<u32*>(&wl[t * WST + c]) = 0;
            }
            for (int i = lane; i < 16 * 27; i += 64) {
                const int t = i / 27, j = 101 + (i - t * 27);
                wb[t * WBST + j] = 0;
            }
            f32x4 dacc[9];
            f32x4 eacc[7];
            #pragma unroll
            for (int i = 0; i < 9; ++i) dacc[i] = zf;
            #pragma unroll
            for (int i = 0; i < 7; ++i) eacc[i] = zf;
            #pragma unroll
            for (int nf = 0; nf < 9; ++nf) {
                dacc[nf] = MFMA16(a0, k0r[nf], dacc[nf], 0, 0, 0);
                dacc[nf] = MFMA16(a1, k1r[nf], dacc[nf], 0, 0, 0);
            }
            #pragma unroll
            for (int jf = 0; jf < 7; ++jf) {
                const u16* ep = embR + (jf * 16 + l15) * 64 + kg8;
                eacc[jf] = MFMA16(a0, ld8(ep), eacc[jf], 0, 0, 0);
                eacc[jf] = MFMA16(a1, ld8(ep + 32), eacc[jf], 0, 0, 0);
            }
            #pragma unroll
            for (int jf = 0; jf < 7; ++jf)
                #pragma unroll
                for (int r = 0; r < 4; ++r) {
                    const int t = (lane >> 4) * 4 + r;
                    bs[t * BST + jf * 16 + l15] = f2bf(eacc[jf][r]);
                }
            #pragma unroll
            for (int nf = 0; nf < 9; ++nf)
                #pragma unroll
                for (int r = 0; r < 4; ++r) {
                    const int t = (lane >> 4) * 4 + r;
                    const int cs = nf * 16 + l15;
                    const int j = cs - t - 14;
                    const int s = tt0 - 64 + cs;
                    float v = dacc[nf][r];
                    if (j >= 0 && j < 101 && s >= 0 && s < 1536)
                        v += bf2f(bs[t * BST + j]);
                    else
                        v = -1e30f;
                    dacc[nf][r] = v;
                }
            float inv[4];
            #pragma unroll
            for (int r = 0; r < 4; ++r) {
                float m = dacc[0][r];
                #pragma unroll
                for (int nf = 1; nf < 9; ++nf) m = fmaxf(m, dacc[nf][r]);
                m = fmaxf(m, __shfl_xor(m, 1));
                m = fmaxf(m, __shfl_xor(m, 2));
                m = fmaxf(m, __shfl_xor(m, 4));
                m = fmaxf(m, __shfl_xor(m, 8));
                float ss = 0.f;
                #pragma unroll
                for (int nf = 0; nf < 9; ++nf) {
                    float e = __expf(dacc[nf][r] - m);
                    dacc[nf][r] = e;
                    ss += e;
                }
                ss += __shfl_xor(ss, 1);
                ss += __shfl_xor(ss, 2);
                ss += __shfl_xor(ss, 4);
                ss += __shfl_xor(ss, 8);
                inv[r] = 1.f / ss;
            }
            #pragma unroll
            for (int nf = 0; nf < 9; ++nf)
                #pragma unroll
                for (int r = 0; r < 4; ++r) {
                    const int t = (lane >> 4) * 4 + r;
                    const int cs = nf * 16 + l15;
                    const u16 w16 = f2bf(dacc[nf][r] * inv[r]);
                    wl[t * WST + cs] = w16;
                    const int j = cs - t - 14;
                    if (j >= 0 && j < 101) wb[t * WBST + j] = w16;
                }
            f32x4 oacc[4];
            #pragma unroll
            for (int i = 0; i < 4; ++i) oacc[i] = zf;
            #pragma unroll
            for (int kf = 0; kf < 5; ++kf) {
                const bf16x8 aw = ld8(&wl[l15 * WST + kf * 32 + kg8]);
                int sb = tt0 - 64 + kf * 32 + kg8;
                int sbc = sb < 0 ? 0 : (sb > 1528 ? 1528 : sb);
                #pragma unroll
                for (int nf = 0; nf < 4; ++nf) {
                    const u16* cp = cbuf + (size_t)(b * 256 + h * 64 + nf * 16 + l15) * 1536 + sbc;
                    oacc[nf] = MFMA16(aw, ld8(cp), oacc[nf], 0, 0, 0);
                }
            }
            #pragma unroll
            for (int kf = 0; kf < 4; ++kf) {
                const bf16x8 ab = ld8(&wb[l15 * WBST + kf * 32 + kg8]);
                #pragma unroll
                for (int nf = 0; nf < 4; ++nf) {
                    const u16* ep = embT + (nf * 16 + l15) * 128 + kf * 32 + kg8;
                    oacc[nf] = MFMA16(ab, ld8(ep), oacc[nf], 0, 0, 0);
                }
            }
            #pragma unroll
            for (int nf = 0; nf < 4; ++nf)
                #pragma unroll
                for (int r = 0; r < 4; ++r) {
                    const int t = (lane >> 4) * 4 + r;
                    abuf[(size_t)(b * 1536 + tt0 + t) * 256 + h * 64 + nf * 16 + l15] =
                        f2bf(oacc[nf][r]);
                }
        }
    }
    gsync(flags, 3);

    // ================= P3: final GEMM (768 wave tiles) =================
    {
        const int u = blk * 4 + wv;
        if (u < 768) {
            const int b = u / 384;
            const int r = u - b * 384;
            const int l0 = (r >> 3) * 32;
            const int ch0 = (r & 7) * 32;
            const u16* ap = wfb + (size_t)(ch0 + l15) * 256 + kg8;
            const u16* bp = abuf + (size_t)(b * 1536 + l0 + l15) * 256 + kg8;
            bf16x8 a0r[8], a1r[8], b0r[8], b1r[8];
            #pragma unroll
            for (int kd = 0; kd < 8; ++kd) {
                a0r[kd] = ld8(ap + kd * 32);
                a1r[kd] = ld8(ap + 4096 + kd * 32);
                b0r[kd] = ld8(bp + kd * 32);
                b1r[kd] = ld8(bp + 4096 + kd * 32);
            }
            f32x4 acc[2][2] = {{zf, zf}, {zf, zf}};
            #pragma unroll
            for (int kd = 0; kd < 8; ++kd) {
                acc[0][0] = MFMA16(a0r[kd], b0r[kd], acc[0][0], 0, 0, 0);
                acc[0][1] = MFMA16(a0r[kd], b1r[kd], acc[0][1], 0, 0, 0);
                acc[1][0] = MFMA16(a1r[kd], b0r[kd], acc[1][0], 0, 0, 0);
                acc[1][1] = MFMA16(a1r[kd], b1r[kd], acc[1][1], 0, 0, 0);
            }
            #pragma unroll
            for (int mf = 0; mf < 2; ++mf)
                #pragma unroll
                for (int r2 = 0; r2 < 4; ++r2) {
                    const int ch = ch0 + mf * 16 + (lane >> 4) * 4 + r2;
                    const float bv = bf[ch];
                    #pragma unroll
                    for (int nf = 0; nf < 2; ++nf)
                        pbuf[(size_t)(b * 256 + ch) * 1536 + l0 + nf * 16 + l15] =
                            f2bf(acc[mf][nf][r2] + bv);
                }
        }
    }
    gsync(flags, 4);

    // ================= P4: BatchNorm + ReLU + scale =================
    {
        const int o = blk;
        float* rs = (float*)smem32;
        float* rq = rs + 4;
        float v[12];
        float sum = 0.f, sumsq = 0.f;
        #pragma unroll
        for (int g = 0; g < 6; ++g) {
            const int b = (g >= 3);
            const int l = (g - 3 * b) * 512 + tid * 2;
            const u32 w = *reinterpret_cast<const u32*>(&pbuf[(size_t)(b * 256 + o) * 1536 + l]);
            const float v0 = __uint_as_float(w << 16);
            const float v1 = __uint_as_float(w & 0xffff0000u);
            v[g * 2] = v0; v[g * 2 + 1] = v1;
            sum += v0 + v1;
            sumsq = fmaf(v0, v0, sumsq);
            sumsq = fmaf(v1, v1, sumsq);
        }
        #pragma unroll
        for (int off = 1; off < 64; off <<= 1) {
            sum += __shfl_xor(sum, off);
            sumsq += __shfl_xor(sumsq, off);
        }
        const int wave = tid >> 6;
        if ((tid & 63) == 0) { rs[wave] = sum; rq[wave] = sumsq; }
        __syncthreads();
        sum = rs[0] + rs[1] + rs[2] + rs[3];
        sumsq = rq[0] + rq[1] + rq[2] + rq[3];
        const float mean = sum * (1.f / 3072.f);
        const float var = sumsq * (1.f / 3072.f) - mean * mean;
        const float is = rsqrtf(var + 1e-5f);
        const float gm = gamma[o] * is;
        const float b2 = beta[o] - mean * gm;
        const float sc = scale[o];
        #pragma unroll
        for (int g = 0; g < 6; ++g) {
            const int b = (g >= 3);
            const int l = (g - 3 * b) * 512 + tid * 2;
            float2 o2;
            o2.x = fmaxf(fmaf(v[g * 2], gm, b2), 0.f) * sc;
            o2.y = fmaxf(fmaf(v[g * 2 + 1], gm, b2), 0.f) * sc;
            *reinterpret_cast<float2*>(&out[(size_t)(b * 256 + o) * 1536 + l]) = o2;
        }
    }
}

extern "C" void kernel_launch(void* const* d_in, const int* in_sizes, int n_in,
                              void* d_out, int out_size, void* d_ws, size_t ws_size,
                              hipStream_t stream) {
    const float* x     = (const float*)d_in[0];
    const float* Wc    = (const float*)d_in[1];
    const float* bc    = (const float*)d_in[2];
    const float* Wq    = (const float*)d_in[3];
    const float* bq    = (const float*)d_in[4];
    const float* Wk    = (const float*)d_in[5];
    const float* bk    = (const float*)d_in[6];
    const float* emb   = (const float*)d_in[7];
    const float* Wf    = (const float*)d_in[8];
    const float* bf    = (const float*)d_in[9];
    const float* gamma = (const float*)d_in[10];
    const float* beta  = (const float*)d_in[11];
    const float* scale = (const float*)d_in[12];
    float* out = (float*)d_out;
    u16* ws = (u16*)d_ws;

    const size_t NLC = 786432;  // B*C*L
    u16* xT   = ws;                 // [2][1536][256]
    u16* qb   = ws + NLC;           // [2][1536][256]
    u16* kb   = ws + 2 * NLC;       // [2][1536][256]
    u16* cbuf = ws + 3 * NLC;       // [2][256][1536]
    u16* abuf = ws + 4 * NLC;       // [2][1536][256]
    u16* pbuf = ws + 5 * NLC;       // [2][256][1536]
    u16* wcb  = ws + 6 * NLC;       // [256][256]
    u16* wqb  = wcb + 65536;
    u16* wkb  = wqb + 65536;
    u16* wfb  = wkb + 65536;
    u16* embR = wfb + 65536;        // [112][64]
    u16* embT = embR + 112 * 64;    // [64][128]
    u32* flags = (u32*)(embT + 64 * 128);   // [256] barrier flags (poison-proof)

    fused_all<<<NBLK, 256, 0, stream>>>(
        x, Wc, bc, Wq, bq, Wk, bk, emb, Wf, bf, gamma, beta, scale,
        xT, wcb, wqb, wkb, wfb, embR, embT, qb, kb, cbuf, abuf, pbuf,
        flags, out);
}

// Round 13
// 124.569 us; speedup vs baseline: 2.5362x; 2.5362x over previous
//
#include <hip/hip_runtime.h>

typedef unsigned short u16;
typedef unsigned int u32;
typedef __bf16 bf16x8 __attribute__((ext_vector_type(8)));
typedef float f32x4 __attribute__((ext_vector_type(4)));

#define MFMA16 __builtin_amdgcn_mfma_f32_16x16x32_bf16

__device__ __forceinline__ u16 f2bf(float f) {
    u32 u = __float_as_uint(f);
    u32 r = (u + 0x7fffu + ((u >> 16) & 1u)) >> 16;
    return (u16)r;
}
__device__ __forceinline__ float bf2f(u16 h) {
    return __uint_as_float(((u32)h) << 16);
}
__device__ __forceinline__ bf16x8 ld8(const u16* p) {
    return *reinterpret_cast<const bf16x8*>(p);
}
// fp32 -> bf16x8 convert-on-load (identical f2bf rounding as the old prep)
__device__ __forceinline__ bf16x8 ld8f(const float* p) {
    const float4 a = *reinterpret_cast<const float4*>(p);
    const float4 b = *reinterpret_cast<const float4*>(p + 4);
    union { bf16x8 v; u16 s[8]; } u;
    u.s[0] = f2bf(a.x); u.s[1] = f2bf(a.y); u.s[2] = f2bf(a.z); u.s[3] = f2bf(a.w);
    u.s[4] = f2bf(b.x); u.s[5] = f2bf(b.y); u.s[6] = f2bf(b.z); u.s[7] = f2bf(b.w);
    return u.v;
}
__device__ __forceinline__ bf16x8 ld8f03(const float* p) {   // 0.3f * v
    const float4 a = *reinterpret_cast<const float4*>(p);
    const float4 b = *reinterpret_cast<const float4*>(p + 4);
    union { bf16x8 v; u16 s[8]; } u;
    u.s[0] = f2bf(0.3f * a.x); u.s[1] = f2bf(0.3f * a.y);
    u.s[2] = f2bf(0.3f * a.z); u.s[3] = f2bf(0.3f * a.w);
    u.s[4] = f2bf(0.3f * b.x); u.s[5] = f2bf(0.3f * b.y);
    u.s[6] = f2bf(0.3f * b.z); u.s[7] = f2bf(0.3f * b.w);
    return u.v;
}
__device__ __forceinline__ bf16x8 zero8() {
    union { bf16x8 v; u16 s[8]; } u;
    #pragma unroll
    for (int e = 0; e < 8; ++e) u.s[e] = 0;
    return u.v;
}

// ---------------------------------------------------------------------------
// gemm_qkc: q/k/content conv1x1 with self-staged x (fp32->bf16 LDS transpose)
// and on-the-fly W conversion. grid (24, 8, 2), 256 thr = 4 waves.
// Wave wv: l-sub = (wv&1)*32, ch-sub = (wv>>1)*16. Bit-identical to r10.
// ---------------------------------------------------------------------------
__global__ __launch_bounds__(256) void gemm_qkc(
    const float* __restrict__ x,
    const float* __restrict__ Wq, const float* __restrict__ bq,
    const float* __restrict__ Wk, const float* __restrict__ bk,
    const float* __restrict__ Wc, const float* __restrict__ bc,
    u16* __restrict__ qo, u16* __restrict__ ko, u16* __restrict__ co)
{
    __shared__ u16 xs[64][264];   // [l][c], row stride 528 B (16B-aligned)
    const int tid = threadIdx.x, wv = tid >> 6, lane = tid & 63;
    const int l15 = lane & 15, kg8 = (lane >> 4) * 8;
    const int l0 = blockIdx.x * 64, ch0 = blockIdx.y * 32, b = blockIdx.z;

    // stage x[b][c][l0..l0+64) -> xs[l][c] bf16 (same f2bf as old prep)
    const int cc = tid >> 2, lq = (tid & 3) * 16;
    #pragma unroll
    for (int it = 0; it < 4; ++it) {
        const int c = it * 64 + cc;
        const float* xp = x + (size_t)((b * 256 + c) * 1536 + l0 + lq);
        #pragma unroll
        for (int i = 0; i < 4; ++i) {
            const float4 v = *reinterpret_cast<const float4*>(xp + i * 4);
            xs[lq + i * 4 + 0][c] = f2bf(v.x);
            xs[lq + i * 4 + 1][c] = f2bf(v.y);
            xs[lq + i * 4 + 2][c] = f2bf(v.z);
            xs[lq + i * 4 + 3][c] = f2bf(v.w);
        }
    }
    __syncthreads();

    const int lw = (wv & 1) * 32;          // wave's l offset in tile
    const int chw = ch0 + (wv >> 1) * 16;  // wave's 16-ch group
    const f32x4 zf = {0.f, 0.f, 0.f, 0.f};

    // x fragments (A for q/k, B for content): rows lw+l15 and lw+16+l15
    bf16x8 xa0[8], xa1[8];
    #pragma unroll
    for (int kd = 0; kd < 8; ++kd) {
        xa0[kd] = ld8(&xs[lw + l15][kd * 32 + kg8]);
        xa1[kd] = ld8(&xs[lw + 16 + l15][kd * 32 + kg8]);
    }

    #pragma unroll
    for (int which = 0; which < 3; ++which) {
        const float* W    = (which == 0) ? Wq : (which == 1) ? Wk : Wc;
        const float* bias = (which == 0) ? bq : (which == 1) ? bk : bc;
        // W fragments: rows chw+l15 (and +16 for content's second... not needed:
        // which<2 uses 1 ch-group; which==2 uses same 16 ch as A)
        bf16x8 wf[8];
        #pragma unroll
        for (int kd = 0; kd < 8; ++kd)
            wf[kd] = ld8f(W + (size_t)(chw + l15) * 256 + kd * 32 + kg8);

        if (which < 2) {
            u16* outp = which ? ko : qo;
            f32x4 acc0 = zf, acc1 = zf;
            #pragma unroll
            for (int kd = 0; kd < 8; ++kd) {
                acc0 = MFMA16(xa0[kd], wf[kd], acc0, 0, 0, 0);
                acc1 = MFMA16(xa1[kd], wf[kd], acc1, 0, 0, 0);
            }
            const float bv = bias[chw + l15];
            #pragma unroll
            for (int r = 0; r < 4; ++r) {
                const int row0 = l0 + lw + (lane >> 4) * 4 + r;
                outp[(size_t)(b * 1536 + row0) * 256 + chw + l15] = f2bf(acc0[r] + bv);
                outp[(size_t)(b * 1536 + row0 + 16) * 256 + chw + l15] = f2bf(acc1[r] + bv);
            }
        } else {
            f32x4 acc0 = zf, acc1 = zf;   // acc_nf: nf=0 -> xa0 cols, nf=1 -> xa1
            #pragma unroll
            for (int kd = 0; kd < 8; ++kd) {
                acc0 = MFMA16(wf[kd], xa0[kd], acc0, 0, 0, 0);
                acc1 = MFMA16(wf[kd], xa1[kd], acc1, 0, 0, 0);
            }
            #pragma unroll
            for (int r = 0; r < 4; ++r) {
                const int ch = chw + (lane >> 4) * 4 + r;
                const float bv = bias[ch];
                co[(size_t)(b * 256 + ch) * 1536 + l0 + lw + l15] = f2bf(acc0[r] + bv);
                co[(size_t)(b * 256 + ch) * 1536 + l0 + lw + 16 + l15] = f2bf(acc1[r] + bv);
            }
        }
    }
}

// ---------------------------------------------------------------------------
// attn_mfma: banded attention; emb converted on the fly (bit-identical values).
// grid (48, 8), 128 thr = 2 waves.
// ---------------------------------------------------------------------------
#define WST 168
#define WBST 136
#define BST 114

__global__ __launch_bounds__(128) void attn_mfma(
    const u16* __restrict__ q, const u16* __restrict__ k,
    const u16* __restrict__ cont, const float* __restrict__ emb,
    u16* __restrict__ outp)
{
    __shared__ u16 wls[2][16][WST];
    __shared__ u16 wbs[2][16][WBST];
    __shared__ u16 bss[2][16][BST];
    const int tid = threadIdx.x;
    const int wv = tid >> 6, lane = tid & 63;
    const int l15 = lane & 15, kg8 = (lane >> 4) * 8;
    const int tt0 = (blockIdx.x * 2 + wv) * 16;
    const int bh = blockIdx.y, b = bh >> 2, h = bh & 3;
    u16* wl = &wls[wv][0][0];
    u16* wb = &wbs[wv][0][0];
    u16* bs = &bss[wv][0][0];

    // hoisted cold-miss loads
    const u16* qp = q + (size_t)(b * 1536 + tt0 + l15) * 256 + h * 64 + kg8;
    const bf16x8 a0 = ld8(qp);
    const bf16x8 a1 = ld8(qp + 32);
    bf16x8 k0r[9], k1r[9];
    #pragma unroll
    for (int nf = 0; nf < 9; ++nf) {
        int s = tt0 - 64 + nf * 16 + l15;
        int sc = s < 0 ? 0 : (s > 1535 ? 1535 : s);
        const u16* kp = k + (size_t)(b * 1536 + sc) * 256 + h * 64 + kg8;
        k0r[nf] = ld8(kp);
        k1r[nf] = ld8(kp + 32);
    }

    for (int i = lane; i < 16 * 8; i += 64) {
        const int t = i >> 3, c = 144 + ((i & 7) << 1);
        *reinterpret_cast<u32*>(&wl[t * WST + c]) = 0;
    }
    for (int i = lane; i < 16 * 27; i += 64) {
        const int t = i / 27, j = 101 + (i - t * 27);
        wb[t * WBST + j] = 0;
    }

    const f32x4 zf = {0.f, 0.f, 0.f, 0.f};
    f32x4 dacc[9];
    f32x4 eacc[7];
    #pragma unroll
    for (int i = 0; i < 9; ++i) dacc[i] = zf;
    #pragma unroll
    for (int i = 0; i < 7; ++i) eacc[i] = zf;

    #pragma unroll
    for (int nf = 0; nf < 9; ++nf) {
        dacc[nf] = MFMA16(a0, k0r[nf], dacc[nf], 0, 0, 0);
        dacc[nf] = MFMA16(a1, k1r[nf], dacc[nf], 0, 0, 0);
    }
    // emb logits: row j = jf*16+l15 -> 0.3*emb[100-j][d], zero if j>100
    #pragma unroll
    for (int jf = 0; jf < 7; ++jf) {
        const int j = jf * 16 + l15;
        bf16x8 e0, e1;
        if (j <= 100) {
            const float* ep = emb + (size_t)(100 - j) * 64;
            e0 = ld8f03(ep + kg8);
            e1 = ld8f03(ep + kg8 + 32);
        } else {
            e0 = zero8();
            e1 = zero8();
        }
        eacc[jf] = MFMA16(a0, e0, eacc[jf], 0, 0, 0);
        eacc[jf] = MFMA16(a1, e1, eacc[jf], 0, 0, 0);
    }
    #pragma unroll
    for (int jf = 0; jf < 7; ++jf)
        #pragma unroll
        for (int r = 0; r < 4; ++r) {
            const int t = (lane >> 4) * 4 + r;
            bs[t * BST + jf * 16 + l15] = f2bf(eacc[jf][r]);
        }
    #pragma unroll
    for (int nf = 0; nf < 9; ++nf)
        #pragma unroll
        for (int r = 0; r < 4; ++r) {
            const int t = (lane >> 4) * 4 + r;
            const int cs = nf * 16 + l15;
            const int j = cs - t - 14;
            const int s = tt0 - 64 + cs;
            float v = dacc[nf][r];
            if (j >= 0 && j < 101 && s >= 0 && s < 1536)
                v += bf2f(bs[t * BST + j]);
            else
                v = -1e30f;
            dacc[nf][r] = v;
        }
    float inv[4];
    #pragma unroll
    for (int r = 0; r < 4; ++r) {
        float m = dacc[0][r];
        #pragma unroll
        for (int nf = 1; nf < 9; ++nf) m = fmaxf(m, dacc[nf][r]);
        m = fmaxf(m, __shfl_xor(m, 1));
        m = fmaxf(m, __shfl_xor(m, 2));
        m = fmaxf(m, __shfl_xor(m, 4));
        m = fmaxf(m, __shfl_xor(m, 8));
        float ss = 0.f;
        #pragma unroll
        for (int nf = 0; nf < 9; ++nf) {
            float e = __expf(dacc[nf][r] - m);
            dacc[nf][r] = e;
            ss += e;
        }
        ss += __shfl_xor(ss, 1);
        ss += __shfl_xor(ss, 2);
        ss += __shfl_xor(ss, 4);
        ss += __shfl_xor(ss, 8);
        inv[r] = 1.f / ss;
    }
    #pragma unroll
    for (int nf = 0; nf < 9; ++nf)
        #pragma unroll
        for (int r = 0; r < 4; ++r) {
            const int t = (lane >> 4) * 4 + r;
            const int cs = nf * 16 + l15;
            const u16 w16 = f2bf(dacc[nf][r] * inv[r]);
            wl[t * WST + cs] = w16;
            const int j = cs - t - 14;
            if (j >= 0 && j < 101) wb[t * WBST + j] = w16;
        }

    f32x4 oacc[4];
    #pragma unroll
    for (int i = 0; i < 4; ++i) oacc[i] = zf;
    #pragma unroll
    for (int kf = 0; kf < 5; ++kf) {
        const bf16x8 aw = ld8(&wl[l15 * WST + kf * 32 + kg8]);
        int sb = tt0 - 64 + kf * 32 + kg8;
        int sbc = sb < 0 ? 0 : (sb > 1528 ? 1528 : sb);
        #pragma unroll
        for (int nf = 0; nf < 4; ++nf) {
            const u16* cp = cont + (size_t)(b * 256 + h * 64 + nf * 16 + l15) * 1536 + sbc;
            oacc[nf] = MFMA16(aw, ld8(cp), oacc[nf], 0, 0, 0);
        }
    }
    // embT B-frags: d = nf*16+l15, j = kf*32+kg8+e; zero-guard j>100
    #pragma unroll
    for (int kf = 0; kf < 4; ++kf) {
        const bf16x8 ab = ld8(&wb[l15 * WBST + kf * 32 + kg8]);
        #pragma unroll
        for (int nf = 0; nf < 4; ++nf) {
            const int d = nf * 16 + l15;
            union { bf16x8 v; u16 s[8]; } u;
            #pragma unroll
            for (int e = 0; e < 8; ++e) {
                const int j = kf * 32 + kg8 + e;
                u.s[e] = (j <= 100) ? f2bf(0.3f * emb[(size_t)(100 - j) * 64 + d]) : (u16)0;
            }
            oacc[nf] = MFMA16(ab, u.v, oacc[nf], 0, 0, 0);
        }
    }
    #pragma unroll
    for (int nf = 0; nf < 4; ++nf)
        #pragma unroll
        for (int r = 0; r < 4; ++r) {
            const int t = (lane >> 4) * 4 + r;
            outp[(size_t)(b * 1536 + tt0 + t) * 256 + h * 64 + nf * 16 + l15] =
                f2bf(oacc[nf][r]);
        }
}

// ---------------------------------------------------------------------------
// gemm_f: final conv1x1; Wf converted on the fly. grid (24,8,2), 128 thr
// ---------------------------------------------------------------------------
__global__ __launch_bounds__(128) void gemm_f(
    const float* __restrict__ Wf, const float* __restrict__ bias,
    const u16* __restrict__ srcT, u16* __restrict__ outp)
{
    const int tid = threadIdx.x, wv = tid >> 6, lane = tid & 63;
    const int l15 = lane & 15, kg8 = (lane >> 4) * 8;
    const int b = blockIdx.z;
    const int l0 = blockIdx.x * 64 + wv * 32;
    const int ch0 = blockIdx.y * 32;
    const u16* bp = srcT + (size_t)(b * 1536 + l0 + l15) * 256 + kg8;

    bf16x8 a0r[8], a1r[8], b0r[8], b1r[8];
    #pragma unroll
    for (int kd = 0; kd < 8; ++kd) {
        a0r[kd] = ld8f(Wf + (size_t)(ch0 + l15) * 256 + kd * 32 + kg8);
        a1r[kd] = ld8f(Wf + (size_t)(ch0 + 16 + l15) * 256 + kd * 32 + kg8);
        b0r[kd] = ld8(bp + kd * 32);
        b1r[kd] = ld8(bp + 4096 + kd * 32);
    }
    const f32x4 zf = {0.f, 0.f, 0.f, 0.f};
    f32x4 acc[2][2] = {{zf, zf}, {zf, zf}};
    #pragma unroll
    for (int kd = 0; kd < 8; ++kd) {
        acc[0][0] = MFMA16(a0r[kd], b0r[kd], acc[0][0], 0, 0, 0);
        acc[0][1] = MFMA16(a0r[kd], b1r[kd], acc[0][1], 0, 0, 0);
        acc[1][0] = MFMA16(a1r[kd], b0r[kd], acc[1][0], 0, 0, 0);
        acc[1][1] = MFMA16(a1r[kd], b1r[kd], acc[1][1], 0, 0, 0);
    }
    #pragma unroll
    for (int mf = 0; mf < 2; ++mf)
        #pragma unroll
        for (int r = 0; r < 4; ++r) {
            const int ch = ch0 + mf * 16 + (lane >> 4) * 4 + r;
            const float bv = bias[ch];
            #pragma unroll
            for (int nf = 0; nf < 2; ++nf)
                outp[(size_t)(b * 256 + ch) * 1536 + l0 + nf * 16 + l15] =
                    f2bf(acc[mf][nf][r] + bv);
        }
}

// ---------------------------------------------------------------------------
// BatchNorm(train) + ReLU + scale (unchanged)
// ---------------------------------------------------------------------------
__global__ __launch_bounds__(256) void bn_apply(
    const u16* __restrict__ pre, const float* __restrict__ gamma,
    const float* __restrict__ beta, const float* __restrict__ scale,
    float* __restrict__ out)
{
    const int o = blockIdx.x;
    const int tid = threadIdx.x;
    float v[12];
    float sum = 0.f, sumsq = 0.f;
    #pragma unroll
    for (int g = 0; g < 6; ++g) {
        const int b = (g >= 3);
        const int l = (g - 3 * b) * 512 + tid * 2;
        const u32 w = *reinterpret_cast<const u32*>(&pre[(size_t)(b * 256 + o) * 1536 + l]);
        const float v0 = __uint_as_float(w << 16);
        const float v1 = __uint_as_float(w & 0xffff0000u);
        v[g * 2] = v0; v[g * 2 + 1] = v1;
        sum += v0 + v1;
        sumsq = fmaf(v0, v0, sumsq);
        sumsq = fmaf(v1, v1, sumsq);
    }
    #pragma unroll
    for (int off = 1; off < 64; off <<= 1) {
        sum += __shfl_xor(sum, off);
        sumsq += __shfl_xor(sumsq, off);
    }
    __shared__ float rs[4], rq[4];
    const int wave = tid >> 6;
    if ((tid & 63) == 0) { rs[wave] = sum; rq[wave] = sumsq; }
    __syncthreads();
    sum = rs[0] + rs[1] + rs[2] + rs[3];
    sumsq = rq[0] + rq[1] + rq[2] + rq[3];
    const float mean = sum * (1.f / 3072.f);
    const float var = sumsq * (1.f / 3072.f) - mean * mean;
    const float is = rsqrtf(var + 1e-5f);
    const float gm = gamma[o] * is;
    const float b2 = beta[o] - mean * gm;
    const float sc = scale[o];
    #pragma unroll
    for (int g = 0; g < 6; ++g) {
        const int b = (g >= 3);
        const int l = (g - 3 * b) * 512 + tid * 2;
        float2 o2;
        o2.x = fmaxf(fmaf(v[g * 2], gm, b2), 0.f) * sc;
        o2.y = fmaxf(fmaf(v[g * 2 + 1], gm, b2), 0.f) * sc;
        *reinterpret_cast<float2*>(&out[(size_t)(b * 256 + o) * 1536 + l]) = o2;
    }
}

extern "C" void kernel_launch(void* const* d_in, const int* in_sizes, int n_in,
                              void* d_out, int out_size, void* d_ws, size_t ws_size,
                              hipStream_t stream) {
    const float* x     = (const float*)d_in[0];
    const float* Wc    = (const float*)d_in[1];
    const float* bc    = (const float*)d_in[2];
    const float* Wq    = (const float*)d_in[3];
    const float* bq    = (const float*)d_in[4];
    const float* Wk    = (const float*)d_in[5];
    const float* bk    = (const float*)d_in[6];
    const float* emb   = (const float*)d_in[7];
    const float* Wf    = (const float*)d_in[8];
    const float* bf    = (const float*)d_in[9];
    const float* gamma = (const float*)d_in[10];
    const float* beta  = (const float*)d_in[11];
    const float* scale = (const float*)d_in[12];
    float* out = (float*)d_out;
    u16* ws = (u16*)d_ws;

    const size_t NLC = 786432;  // B*C*L
    u16* qb   = ws;                 // [2][1536][256]
    u16* kb   = ws + NLC;           // [2][1536][256]
    u16* cbuf = ws + 2 * NLC;       // [2][256][1536]
    u16* abuf = ws + 3 * NLC;       // [2][1536][256]
    u16* pbuf = ws + 4 * NLC;       // [2][256][1536]

    gemm_qkc<<<dim3(24, 8, 2), 256, 0, stream>>>(x, Wq, bq, Wk, bk, Wc, bc,
                                                 qb, kb, cbuf);
    attn_mfma<<<dim3(48, 8), 128, 0, stream>>>(qb, kb, cbuf, emb, abuf);
    gemm_f<<<dim3(24, 8, 2), 128, 0, stream>>>(Wf, bf, abuf, pbuf);
    bn_apply<<<256, 256, 0, stream>>>(pbuf, gamma, beta, scale, out);
}